// Round 7
// baseline (1497.909 us; speedup 1.0000x reference)
//
#include <hip/hip_runtime.h>

typedef unsigned short u16;
typedef unsigned int u32;

typedef __attribute__((ext_vector_type(8))) short bf16x8;
typedef __attribute__((ext_vector_type(4))) float f32x4;
typedef __attribute__((ext_vector_type(2))) float f32x2;

// ---------- helpers ----------
__device__ __forceinline__ float bf2f(u16 v) {
    union { u32 i; float f; } u; u.i = ((u32)v) << 16; return u.f;
}
__device__ __forceinline__ u16 f2bf(float f) {
    union { float f; u32 i; } u; u.f = f;
    u32 r = u.i + 0x7FFFu + ((u.i >> 16) & 1u);   // RNE
    return (u16)(r >> 16);
}
__device__ __forceinline__ u32 pack2(float lo, float hi) {
    return (u32)f2bf(lo) | ((u32)f2bf(hi) << 16);
}
__device__ __forceinline__ void unpack8(uint4 r, float* o) {
    o[0] = __uint_as_float(r.x << 16); o[1] = __uint_as_float(r.x & 0xffff0000u);
    o[2] = __uint_as_float(r.y << 16); o[3] = __uint_as_float(r.y & 0xffff0000u);
    o[4] = __uint_as_float(r.z << 16); o[5] = __uint_as_float(r.z & 0xffff0000u);
    o[6] = __uint_as_float(r.w << 16); o[7] = __uint_as_float(r.w & 0xffff0000u);
}
// unpack a uint4 (8 bf16) into 4 float2 pairs (v_pk-friendly)
__device__ __forceinline__ void unpack8p(uint4 r, f32x2* o) {
    o[0] = (f32x2){__uint_as_float(r.x << 16), __uint_as_float(r.x & 0xffff0000u)};
    o[1] = (f32x2){__uint_as_float(r.y << 16), __uint_as_float(r.y & 0xffff0000u)};
    o[2] = (f32x2){__uint_as_float(r.z << 16), __uint_as_float(r.z & 0xffff0000u)};
    o[3] = (f32x2){__uint_as_float(r.w << 16), __uint_as_float(r.w & 0xffff0000u)};
}
__device__ __forceinline__ f32x2 pk_fma(f32x2 a, f32x2 b, f32x2 c) {
#if __has_builtin(__builtin_elementwise_fma)
    return __builtin_elementwise_fma(a, b, c);
#else
    return a * b + c;
#endif
}
__device__ __forceinline__ void async16(const void* g, void* l) {
    __builtin_amdgcn_global_load_lds((const __attribute__((address_space(1))) void*)g,
                                     (__attribute__((address_space(3))) void*)l, 16, 0, 0);
}
// DPP butterfly adds (VALU-only, no LDS pipe)
template<int CTRL>
__device__ __forceinline__ float dpp_add(float x) {
    int y = __builtin_amdgcn_update_dpp(0, __float_as_int(x), CTRL, 0xf, 0xf, true);
    return x + __int_as_float(y);
}
__device__ __forceinline__ float row16_allreduce(float x) {
    x = dpp_add<0xB1>(x);    // xor 1
    x = dpp_add<0x4E>(x);    // xor 2
    x = dpp_add<0x141>(x);   // row_half_mirror
    x = dpp_add<0x140>(x);   // row_mirror
    return x;
}
__device__ __forceinline__ float row8_allreduce(float x) {
    x = dpp_add<0xB1>(x);    // xor 1
    x = dpp_add<0x4E>(x);    // xor 2
    x = dpp_add<0x141>(x);   // row_half_mirror (completes 8-lane group)
    return x;
}

// ---------- fp32 -> bf16 convert (elementwise, 8/thread) ----------
__global__ __launch_bounds__(256) void f2b_kernel(const float* __restrict__ in,
                                                  u16* __restrict__ out)
{
    long i = ((long)blockIdx.x * 256 + threadIdx.x) * 8;
    float4 a = *(const float4*)&in[i], b = *(const float4*)&in[i + 4];
    uint4 o = make_uint4(pack2(a.x, a.y), pack2(a.z, a.w), pack2(b.x, b.y), pack2(b.z, b.w));
    *(uint4*)&out[i] = o;
}

// ---------- fp32 RxC -> bf16 CxR transpose ----------
__global__ __launch_bounds__(256) void transpose_f2b(const float* __restrict__ in,
                                                     u16* __restrict__ out, int R, int C)
{
    __shared__ float tile[32][33];
    const int r0 = blockIdx.y * 32, c0 = blockIdx.x * 32;
    const int tr = threadIdx.x >> 3;
    const int tc = (threadIdx.x & 7) * 4;
    float4 v = *(const float4*)&in[(long)(r0 + tr) * C + c0 + tc];
    tile[tr][tc] = v.x; tile[tr][tc + 1] = v.y; tile[tr][tc + 2] = v.z; tile[tr][tc + 3] = v.w;
    __syncthreads();
    uint2 o;
    o.x = pack2(tile[tc][tr], tile[tc + 1][tr]);
    o.y = pack2(tile[tc + 2][tr], tile[tc + 3][tr]);
    *(uint2*)&out[(long)(c0 + tr) * R + r0 + tc] = o;
}

// ---------- GEMM (m97-style): C(MxN) = A(MxK) * Bt(NxK)^T, bf16 in, fp32 acc ----------
template<int CF>   // CF=1: C fp32, CF=0: C bf16
__global__ __launch_bounds__(256) void gemm_bt(const u16* __restrict__ A,
                                               const u16* __restrict__ Bt,
                                               void* __restrict__ Cp,
                                               int M, int N, int K)
{
    __shared__ __align__(16) u16 As[128 * 32];
    __shared__ __align__(16) u16 Bs[128 * 32];

    const int tid = threadIdx.x;
    const int lane = tid & 63;
    const int wave = tid >> 6;
    const int wm = (wave >> 1) * 64;
    const int wn = (wave & 1) * 64;
    const int lanelo = lane & 15;
    const int quad = lane >> 4;
    const long m0 = (long)blockIdx.y * 128;
    const long n0 = (long)blockIdx.x * 128;

    f32x4 acc[4][4];
#pragma unroll
    for (int i = 0; i < 4; ++i)
#pragma unroll
        for (int j = 0; j < 4; ++j) acc[i][j] = (f32x4)0.0f;

    const u16* agp0 = A + (long)(m0 + wave * 16 + (lane >> 2)) * K + (lane & 3) * 8;
    const u16* agp1 = agp0 + 64 * (long)K;
    const u16* bgp0 = Bt + (long)(n0 + wave * 16 + (lane >> 2)) * K + (lane & 3) * 8;
    const u16* bgp1 = bgp0 + 64 * (long)K;
    u16* lA0 = &As[wave * 16 * 32];
    u16* lA1 = &As[(wave * 16 + 64) * 32];
    u16* lB0 = &Bs[wave * 16 * 32];
    u16* lB1 = &Bs[(wave * 16 + 64) * 32];

    for (int k0 = 0; k0 < K; k0 += 32) {
        __syncthreads();
        async16(agp0 + k0, lA0);
        async16(agp1 + k0, lA1);
        async16(bgp0 + k0, lB0);
        async16(bgp1 + k0, lB1);
        __syncthreads();

        bf16x8 af[4], bf[4];
#pragma unroll
        for (int mt = 0; mt < 4; ++mt)
            af[mt] = *(const bf16x8*)&As[(wm + mt * 16 + lanelo) * 32 + quad * 8];
#pragma unroll
        for (int nt = 0; nt < 4; ++nt)
            bf[nt] = *(const bf16x8*)&Bs[(wn + nt * 16 + lanelo) * 32 + quad * 8];
#pragma unroll
        for (int mt = 0; mt < 4; ++mt)
#pragma unroll
            for (int nt = 0; nt < 4; ++nt)
                acc[mt][nt] = __builtin_amdgcn_mfma_f32_16x16x32_bf16(af[mt], bf[nt], acc[mt][nt], 0, 0, 0);
    }

#pragma unroll
    for (int mt = 0; mt < 4; ++mt)
#pragma unroll
        for (int nt = 0; nt < 4; ++nt)
#pragma unroll
            for (int r = 0; r < 4; ++r) {
                long row = m0 + wm + mt * 16 + quad * 4 + r;
                long col = n0 + wn + nt * 16 + lanelo;
                if constexpr (CF) ((float*)Cp)[row * N + col] = acc[mt][nt][r];
                else              ((u16*)Cp)[row * N + col] = f2bf(acc[mt][nt][r]);
            }
}

// ---------- ba = hs @ w_ba (2048x64) with g/beta epilogue ----------
__global__ __launch_bounds__(256) void ba_kernel(const float* __restrict__ hs,
                                                 const float* __restrict__ wba,
                                                 const float* __restrict__ A_log,
                                                 const float* __restrict__ dt_bias,
                                                 float* __restrict__ gbuf,
                                                 float* __restrict__ bbuf)
{
    const int m = blockIdx.x * 4 + (threadIdx.x >> 6);
    const int n = threadIdx.x & 63;
    const float* hrow = &hs[(long)m * 2048];
    float acc = 0.f;
#pragma unroll 8
    for (int k = 0; k < 2048; ++k)
        acc += hrow[k] * wba[(long)k * 64 + n];
    const int hk4 = n >> 2, r = n & 3;
    if (r < 2) {
        bbuf[(long)m * 32 + hk4 * 2 + r] = 1.f / (1.f + expf(-acc));
    } else {
        const int hv = hk4 * 2 + (r - 2);
        float x = acc + dt_bias[hv];
        float sp = (x > 20.f) ? x : log1pf(expf(x));
        gbuf[(long)m * 32 + hv] = -expf(A_log[hv]) * sp;
    }
}

// ---------- causal depthwise conv (K=4) + silu + per-head l2norm, 8 ch/thread ----------
__global__ __launch_bounds__(256) void conv_kernel(const u16* __restrict__ qkvz,
                                                   const float* __restrict__ cw,
                                                   u16* __restrict__ out)
{
    const int bid = blockIdx.x;          // bs*4 + part
    const int bs = bid >> 2, part = bid & 3;
    const int c = part * 2048 + threadIdx.x * 8;
    int n;
    if (c < 2048)       n = (c >> 7) * 768 + (c & 127);
    else if (c < 4096) { int c2 = c - 2048; n = (c2 >> 7) * 768 + 128 + (c2 & 127); }
    else               { int c2 = c - 4096; n = (c2 >> 8) * 768 + 256 + (c2 & 255); }
    const int s = bs & 2047;
    const long base = (long)bs * 12288 + n;

    float x0[8], x1[8], x2[8], x3[8];
#pragma unroll
    for (int i = 0; i < 8; ++i) { x0[i] = 0.f; x1[i] = 0.f; x2[i] = 0.f; }
    { uint4 r = *(const uint4*)&qkvz[base]; unpack8(r, x3); }
    if (s >= 1) { uint4 r = *(const uint4*)&qkvz[base - 12288];     unpack8(r, x2); }
    if (s >= 2) { uint4 r = *(const uint4*)&qkvz[base - 2 * 12288]; unpack8(r, x1); }
    if (s >= 3) { uint4 r = *(const uint4*)&qkvz[base - 3 * 12288]; unpack8(r, x0); }

    float v[8]; float ss = 0.f;
#pragma unroll
    for (int i = 0; i < 8; ++i) {
        float4 w = *(const float4*)&cw[(c + i) * 4];
        float a = x0[i] * w.x + x1[i] * w.y + x2[i] * w.z + x3[i] * w.w;
        v[i] = a / (1.f + expf(-a));
        ss += v[i] * v[i];
    }
    if (part < 2) {   // q/k: l2norm over 128-ch head = 16 consecutive lanes
        ss = row16_allreduce(ss);
        float rn = rsqrtf(ss + 1e-6f);
#pragma unroll
        for (int i = 0; i < 8; ++i) v[i] *= rn;
    }
    uint4 o = make_uint4(pack2(v[0], v[1]), pack2(v[2], v[3]), pack2(v[4], v[5]), pack2(v[6], v[7]));
    *(uint4*)&out[(long)bs * 8192 + c] = o;
}

// ---------- sequential gated delta scan (v3: rg8 x S[16], packed-f32 math) ----------
// grid 512 = (b, h, col-block of 16); 128 threads = 2 waves.
// Wave w handles cols c0 + w*8 + cg (cg = lane>>3); rg = lane&7 owns rows rg*16..+15.
// State = 8 float2 (16 rows) per lane. DPP 8-lane reduces; v_pk_fma_f32 math.
__global__ __launch_bounds__(128) void scan_kernel(const u16* __restrict__ conv,
                                                   const float* __restrict__ gbuf,
                                                   const float* __restrict__ bbuf,
                                                   u16* __restrict__ obuf)
{
    __shared__ __align__(16) u16 lq16[32 * 128];
    __shared__ __align__(16) u16 lk16[32 * 128];
    __shared__ __align__(16) u16 lv16[32 * 16];
    __shared__ float lgb[64];   // interleaved {eg, be}

    const int bid = blockIdx.x;
    const int b = bid >> 8;
    const int h = (bid >> 3) & 31;
    const int c0 = (bid & 7) * 16;
    const int hk = h >> 1;
    const int tid = threadIdx.x;        // 0..127
    const int lane = tid & 63;
    const int rg = lane & 7;
    const int vcol = (tid >> 6) * 8 + (lane >> 3);   // 0..15
    const long rowbase = (long)b * 2048;
    const float scale = 0.08838834764831845f;  // 128^-0.5

    f32x2 S2[8];
#pragma unroll
    for (int i = 0; i < 8; ++i) S2[i] = (f32x2){0.f, 0.f};

    for (int t0 = 0; t0 < 2048; t0 += 32) {
        __syncthreads();
        // stage q,k raw bf16: 512 uint4 each across 128 threads
#pragma unroll
        for (int p = 0; p < 4; ++p) {
            const int id = tid + p * 128;
            const int tt = id >> 4, u4 = id & 15;
            const long base = (rowbase + t0 + tt) * 8192;
            async16(&conv[base + hk * 128 + u4 * 8], &lq16[id * 8]);
            async16(&conv[base + 2048 + hk * 128 + u4 * 8], &lk16[id * 8]);
        }
        if (tid < 64) {
            const int tt = tid >> 1, c8 = (tid & 1) * 8;
            async16(&conv[(rowbase + t0 + tt) * 8192 + 4096 + h * 128 + c0 + c8], &lv16[tid * 8]);
        }
        if (tid < 32) {
            lgb[2 * tid]     = expf(gbuf[(rowbase + t0 + tid) * 32 + h]);
            lgb[2 * tid + 1] = bbuf[(rowbase + t0 + tid) * 32 + h];
        }
        __syncthreads();

        f32x2 k2[2][8], q2[2][8];
        float vvp[2], egp[2], bep[2];
        {
            uint4 ka = *(const uint4*)&lk16[rg * 16];
            uint4 kb = *(const uint4*)&lk16[rg * 16 + 8];
            unpack8p(ka, &k2[0][0]); unpack8p(kb, &k2[0][4]);
            uint4 qa = *(const uint4*)&lq16[rg * 16];
            uint4 qb = *(const uint4*)&lq16[rg * 16 + 8];
            unpack8p(qa, &q2[0][0]); unpack8p(qb, &q2[0][4]);
            vvp[0] = bf2f(lv16[vcol]); egp[0] = lgb[0]; bep[0] = lgb[1];
        }
#pragma unroll
        for (int tt = 0; tt < 32; ++tt) {
            const int cur = tt & 1, nxt = cur ^ 1;
            if (tt < 31) {  // prefetch + unpack t+1 while computing t
                const int o = (tt + 1) * 128 + rg * 16;
                uint4 ka = *(const uint4*)&lk16[o];
                uint4 kb = *(const uint4*)&lk16[o + 8];
                unpack8p(ka, &k2[nxt][0]); unpack8p(kb, &k2[nxt][4]);
                uint4 qa = *(const uint4*)&lq16[o];
                uint4 qb = *(const uint4*)&lq16[o + 8];
                unpack8p(qa, &q2[nxt][0]); unpack8p(qb, &q2[nxt][4]);
                vvp[nxt] = bf2f(lv16[(tt + 1) * 16 + vcol]);
                egp[nxt] = lgb[2 * tt + 2]; bep[nxt] = lgb[2 * tt + 3];
            }
            const float eg = egp[cur], be = bep[cur], vv = vvp[cur];
            const f32x2* k8 = k2[cur];
            const f32x2* q8 = q2[cur];
            f32x2 pa = k8[0] * S2[0];
            f32x2 pb = k8[1] * S2[1];
            pa = pk_fma(k8[2], S2[2], pa); pb = pk_fma(k8[3], S2[3], pb);
            pa = pk_fma(k8[4], S2[4], pa); pb = pk_fma(k8[5], S2[5], pb);
            pa = pk_fma(k8[6], S2[6], pa); pb = pk_fma(k8[7], S2[7], pb);
            pa = pa + pb;
            const float pp = row8_allreduce(pa.x + pa.y);
            const float delta = be * (vv - pp * eg);
            const f32x2 eg2 = {eg, eg}, de2 = {delta, delta};
#pragma unroll
            for (int j = 0; j < 8; ++j)
                S2[j] = pk_fma(S2[j], eg2, k8[j] * de2);
            f32x2 oa = q8[0] * S2[0];
            f32x2 ob = q8[1] * S2[1];
            oa = pk_fma(q8[2], S2[2], oa); ob = pk_fma(q8[3], S2[3], ob);
            oa = pk_fma(q8[4], S2[4], oa); ob = pk_fma(q8[5], S2[5], ob);
            oa = pk_fma(q8[6], S2[6], oa); ob = pk_fma(q8[7], S2[7], ob);
            oa = oa + ob;
            const float oo = row8_allreduce(oa.x + oa.y);
            if (rg == 0)
                obuf[((rowbase + t0 + tt) * 32 + h) * 128 + c0 + vcol] = f2bf(oo * scale);
        }
    }
}

// ---------- RMS-norm + gating: y = o*rsqrt(mean(o^2)+eps) * norm_w * silu(z) ----------
__global__ __launch_bounds__(128) void gate_kernel(const u16* __restrict__ obuf,
                                                   const u16* __restrict__ qkvz,
                                                   const float* __restrict__ norm_w,
                                                   u16* __restrict__ ybuf)
{
    const int bid = blockIdx.x;          // bs*32 + hv
    const int bs = bid >> 5, hv = bid & 31;
    const int dv = threadIdx.x;
    __shared__ float red[2];
    float v = bf2f(obuf[(long)bid * 128 + dv]);
    float ss = v * v;
    ss += __shfl_xor(ss, 1);  ss += __shfl_xor(ss, 2);  ss += __shfl_xor(ss, 4);
    ss += __shfl_xor(ss, 8);  ss += __shfl_xor(ss, 16); ss += __shfl_xor(ss, 32);
    if ((dv & 63) == 0) red[dv >> 6] = ss;
    __syncthreads();
    const float mean = (red[0] + red[1]) * (1.f / 128.f);
    const float rstd = rsqrtf(mean + 1e-6f);
    const int hk = hv >> 1;
    const float z = bf2f(qkvz[(long)bs * 12288 + hk * 768 + 512 + (hv & 1) * 128 + dv]);
    const float y = v * rstd * norm_w[dv] * (z / (1.f + expf(-z)));
    ybuf[(long)bs * 4096 + hv * 128 + dv] = f2bf(y);
}

// ---------- launch ----------
extern "C" void kernel_launch(void* const* d_in, const int* in_sizes, int n_in,
                              void* d_out, int out_size, void* d_ws, size_t ws_size,
                              hipStream_t stream)
{
    const float* hs      = (const float*)d_in[0];
    const float* w_qkvz  = (const float*)d_in[1];
    const float* w_ba    = (const float*)d_in[2];
    const float* conv_w  = (const float*)d_in[3];
    const float* A_log   = (const float*)d_in[4];
    const float* dt_bias = (const float*)d_in[5];
    const float* norm_w  = (const float*)d_in[6];
    const float* w_out   = (const float*)d_in[7];

    char* ws = (char*)d_ws;
    u16*   qkvz   = (u16*)ws;                          // 100,663,296 B
    u16*   convb  = (u16*)(ws + 100663296);            //  67,108,864 B
    float* gbuf   = (float*)(ws + 167772160);          //     524,288 B
    float* bbuf   = (float*)(ws + 168296448);          //     524,288 B
    char*  regE   = ws + 168820736;                    //  33,554,432 B (end 202,375,168)
    u16*   hs_b   = (u16*)regE;                        // bf16 hs (dead after GEMM1)
    u16*   obuf   = (u16*)regE;                        // overwrites hs_b at scan time
    u16*   wqkvz_t = convb;                            // bf16 w_qkvz^T (dead after GEMM1; conv overwrites)
    u16*   ybuf   = convb;                             // gate output (conv data dead after scan)
    u16*   wout_t = qkvz;                              // bf16 w_out^T (qkvz dead after gate)

    // 1) dtype prep
    f2b_kernel<<<4096, 256, 0, stream>>>(hs, hs_b);                            // 4096*2048
    transpose_f2b<<<dim3(384, 64), 256, 0, stream>>>(w_qkvz, wqkvz_t, 2048, 12288);
    // 2) qkvz = hs @ w_qkvz  (4096 x 12288 x 2048), bf16 out
    gemm_bt<0><<<dim3(96, 32), 256, 0, stream>>>(hs_b, wqkvz_t, qkvz, 4096, 12288, 2048);
    // 3) g/beta
    ba_kernel<<<1024, 256, 0, stream>>>(hs, w_ba, A_log, dt_bias, gbuf, bbuf);
    // 4) conv + silu + l2norm (overwrites wqkvz_t region)
    conv_kernel<<<4096 * 4, 256, 0, stream>>>(qkvz, conv_w, convb);
    // 5) gated delta scan (overwrites hs_b region)
    scan_kernel<<<512, 128, 0, stream>>>(convb, gbuf, bbuf, obuf);
    // 6) gating (writes ybuf = convb region)
    gate_kernel<<<4096 * 32, 128, 0, stream>>>(obuf, qkvz, norm_w, ybuf);
    // 7) w_out^T into qkvz region (dead), then out = y @ w_out (4096 x 2048 x 4096), fp32 out
    transpose_f2b<<<dim3(64, 128), 256, 0, stream>>>(w_out, wout_t, 4096, 2048);
    gemm_bt<1><<<dim3(16, 32), 256, 0, stream>>>(ybuf, wout_t, d_out, 4096, 2048, 4096);
}

// Round 8
// 1283.656 us; speedup vs baseline: 1.1669x; 1.1669x over previous
//
#include <hip/hip_runtime.h>

typedef unsigned short u16;
typedef unsigned int u32;

typedef __attribute__((ext_vector_type(8))) short bf16x8;
typedef __attribute__((ext_vector_type(4))) float f32x4;
typedef __attribute__((ext_vector_type(2))) float f32x2;

// ---------- helpers ----------
__device__ __forceinline__ float bf2f(u16 v) {
    union { u32 i; float f; } u; u.i = ((u32)v) << 16; return u.f;
}
__device__ __forceinline__ u16 f2bf(float f) {
    union { float f; u32 i; } u; u.f = f;
    u32 r = u.i + 0x7FFFu + ((u.i >> 16) & 1u);   // RNE
    return (u16)(r >> 16);
}
__device__ __forceinline__ u32 pack2(float lo, float hi) {
    return (u32)f2bf(lo) | ((u32)f2bf(hi) << 16);
}
__device__ __forceinline__ void unpack8(uint4 r, float* o) {
    o[0] = __uint_as_float(r.x << 16); o[1] = __uint_as_float(r.x & 0xffff0000u);
    o[2] = __uint_as_float(r.y << 16); o[3] = __uint_as_float(r.y & 0xffff0000u);
    o[4] = __uint_as_float(r.z << 16); o[5] = __uint_as_float(r.z & 0xffff0000u);
    o[6] = __uint_as_float(r.w << 16); o[7] = __uint_as_float(r.w & 0xffff0000u);
}
// unpack a uint4 (8 bf16) into 4 float2 pairs (v_pk-friendly)
__device__ __forceinline__ void unpack8p(uint4 r, f32x2* o) {
    o[0] = (f32x2){__uint_as_float(r.x << 16), __uint_as_float(r.x & 0xffff0000u)};
    o[1] = (f32x2){__uint_as_float(r.y << 16), __uint_as_float(r.y & 0xffff0000u)};
    o[2] = (f32x2){__uint_as_float(r.z << 16), __uint_as_float(r.z & 0xffff0000u)};
    o[3] = (f32x2){__uint_as_float(r.w << 16), __uint_as_float(r.w & 0xffff0000u)};
}
__device__ __forceinline__ f32x2 pk_fma(f32x2 a, f32x2 b, f32x2 c) {
#if __has_builtin(__builtin_elementwise_fma)
    return __builtin_elementwise_fma(a, b, c);
#else
    return a * b + c;
#endif
}
__device__ __forceinline__ void async16(const void* g, void* l) {
    __builtin_amdgcn_global_load_lds((const __attribute__((address_space(1))) void*)g,
                                     (__attribute__((address_space(3))) void*)l, 16, 0, 0);
}
// DPP butterfly adds (VALU-only, no LDS pipe)
template<int CTRL>
__device__ __forceinline__ float dpp_add(float x) {
    int y = __builtin_amdgcn_update_dpp(0, __float_as_int(x), CTRL, 0xf, 0xf, true);
    return x + __int_as_float(y);
}
__device__ __forceinline__ float row16_allreduce(float x) {
    x = dpp_add<0xB1>(x);    // xor 1
    x = dpp_add<0x4E>(x);    // xor 2
    x = dpp_add<0x141>(x);   // row_half_mirror
    x = dpp_add<0x140>(x);   // row_mirror
    return x;
}

// ---------- fp32 -> bf16 convert (elementwise, 8/thread) ----------
__global__ __launch_bounds__(256) void f2b_kernel(const float* __restrict__ in,
                                                  u16* __restrict__ out)
{
    long i = ((long)blockIdx.x * 256 + threadIdx.x) * 8;
    float4 a = *(const float4*)&in[i], b = *(const float4*)&in[i + 4];
    uint4 o = make_uint4(pack2(a.x, a.y), pack2(a.z, a.w), pack2(b.x, b.y), pack2(b.z, b.w));
    *(uint4*)&out[i] = o;
}

// ---------- fp32 RxC -> bf16 CxR transpose ----------
__global__ __launch_bounds__(256) void transpose_f2b(const float* __restrict__ in,
                                                     u16* __restrict__ out, int R, int C)
{
    __shared__ float tile[32][33];
    const int r0 = blockIdx.y * 32, c0 = blockIdx.x * 32;
    const int tr = threadIdx.x >> 3;
    const int tc = (threadIdx.x & 7) * 4;
    float4 v = *(const float4*)&in[(long)(r0 + tr) * C + c0 + tc];
    tile[tr][tc] = v.x; tile[tr][tc + 1] = v.y; tile[tr][tc + 2] = v.z; tile[tr][tc + 3] = v.w;
    __syncthreads();
    uint2 o;
    o.x = pack2(tile[tc][tr], tile[tc + 1][tr]);
    o.y = pack2(tile[tc + 2][tr], tile[tc + 3][tr]);
    *(uint2*)&out[(long)(c0 + tr) * R + r0 + tc] = o;
}

// ---------- GEMM (m97-style): C(MxN) = A(MxK) * Bt(NxK)^T, bf16 in, fp32 acc ----------
template<int CF>   // CF=1: C fp32, CF=0: C bf16
__global__ __launch_bounds__(256) void gemm_bt(const u16* __restrict__ A,
                                               const u16* __restrict__ Bt,
                                               void* __restrict__ Cp,
                                               int M, int N, int K)
{
    __shared__ __align__(16) u16 As[128 * 32];
    __shared__ __align__(16) u16 Bs[128 * 32];

    const int tid = threadIdx.x;
    const int lane = tid & 63;
    const int wave = tid >> 6;
    const int wm = (wave >> 1) * 64;
    const int wn = (wave & 1) * 64;
    const int lanelo = lane & 15;
    const int quad = lane >> 4;
    const long m0 = (long)blockIdx.y * 128;
    const long n0 = (long)blockIdx.x * 128;

    f32x4 acc[4][4];
#pragma unroll
    for (int i = 0; i < 4; ++i)
#pragma unroll
        for (int j = 0; j < 4; ++j) acc[i][j] = (f32x4)0.0f;

    const u16* agp0 = A + (long)(m0 + wave * 16 + (lane >> 2)) * K + (lane & 3) * 8;
    const u16* agp1 = agp0 + 64 * (long)K;
    const u16* bgp0 = Bt + (long)(n0 + wave * 16 + (lane >> 2)) * K + (lane & 3) * 8;
    const u16* bgp1 = bgp0 + 64 * (long)K;
    u16* lA0 = &As[wave * 16 * 32];
    u16* lA1 = &As[(wave * 16 + 64) * 32];
    u16* lB0 = &Bs[wave * 16 * 32];
    u16* lB1 = &Bs[(wave * 16 + 64) * 32];

    for (int k0 = 0; k0 < K; k0 += 32) {
        __syncthreads();
        async16(agp0 + k0, lA0);
        async16(agp1 + k0, lA1);
        async16(bgp0 + k0, lB0);
        async16(bgp1 + k0, lB1);
        __syncthreads();

        bf16x8 af[4], bf[4];
#pragma unroll
        for (int mt = 0; mt < 4; ++mt)
            af[mt] = *(const bf16x8*)&As[(wm + mt * 16 + lanelo) * 32 + quad * 8];
#pragma unroll
        for (int nt = 0; nt < 4; ++nt)
            bf[nt] = *(const bf16x8*)&Bs[(wn + nt * 16 + lanelo) * 32 + quad * 8];
#pragma unroll
        for (int mt = 0; mt < 4; ++mt)
#pragma unroll
            for (int nt = 0; nt < 4; ++nt)
                acc[mt][nt] = __builtin_amdgcn_mfma_f32_16x16x32_bf16(af[mt], bf[nt], acc[mt][nt], 0, 0, 0);
    }

#pragma unroll
    for (int mt = 0; mt < 4; ++mt)
#pragma unroll
        for (int nt = 0; nt < 4; ++nt)
#pragma unroll
            for (int r = 0; r < 4; ++r) {
                long row = m0 + wm + mt * 16 + quad * 4 + r;
                long col = n0 + wn + nt * 16 + lanelo;
                if constexpr (CF) ((float*)Cp)[row * N + col] = acc[mt][nt][r];
                else              ((u16*)Cp)[row * N + col] = f2bf(acc[mt][nt][r]);
            }
}

// ---------- ba = hs @ w_ba (2048x64) with g/beta epilogue ----------
__global__ __launch_bounds__(256) void ba_kernel(const float* __restrict__ hs,
                                                 const float* __restrict__ wba,
                                                 const float* __restrict__ A_log,
                                                 const float* __restrict__ dt_bias,
                                                 float* __restrict__ gbuf,
                                                 float* __restrict__ bbuf)
{
    const int m = blockIdx.x * 4 + (threadIdx.x >> 6);
    const int n = threadIdx.x & 63;
    const float* hrow = &hs[(long)m * 2048];
    float acc = 0.f;
#pragma unroll 8
    for (int k = 0; k < 2048; ++k)
        acc += hrow[k] * wba[(long)k * 64 + n];
    const int hk4 = n >> 2, r = n & 3;
    if (r < 2) {
        bbuf[(long)m * 32 + hk4 * 2 + r] = 1.f / (1.f + expf(-acc));
    } else {
        const int hv = hk4 * 2 + (r - 2);
        float x = acc + dt_bias[hv];
        float sp = (x > 20.f) ? x : log1pf(expf(x));
        gbuf[(long)m * 32 + hv] = -expf(A_log[hv]) * sp;
    }
}

// ---------- causal depthwise conv (K=4) + silu + per-head l2norm, 8 ch/thread ----------
__global__ __launch_bounds__(256) void conv_kernel(const u16* __restrict__ qkvz,
                                                   const float* __restrict__ cw,
                                                   u16* __restrict__ out)
{
    const int bid = blockIdx.x;          // bs*4 + part
    const int bs = bid >> 2, part = bid & 3;
    const int c = part * 2048 + threadIdx.x * 8;
    int n;
    if (c < 2048)       n = (c >> 7) * 768 + (c & 127);
    else if (c < 4096) { int c2 = c - 2048; n = (c2 >> 7) * 768 + 128 + (c2 & 127); }
    else               { int c2 = c - 4096; n = (c2 >> 8) * 768 + 256 + (c2 & 255); }
    const int s = bs & 2047;
    const long base = (long)bs * 12288 + n;

    float x0[8], x1[8], x2[8], x3[8];
#pragma unroll
    for (int i = 0; i < 8; ++i) { x0[i] = 0.f; x1[i] = 0.f; x2[i] = 0.f; }
    { uint4 r = *(const uint4*)&qkvz[base]; unpack8(r, x3); }
    if (s >= 1) { uint4 r = *(const uint4*)&qkvz[base - 12288];     unpack8(r, x2); }
    if (s >= 2) { uint4 r = *(const uint4*)&qkvz[base - 2 * 12288]; unpack8(r, x1); }
    if (s >= 3) { uint4 r = *(const uint4*)&qkvz[base - 3 * 12288]; unpack8(r, x0); }

    float v[8]; float ss = 0.f;
#pragma unroll
    for (int i = 0; i < 8; ++i) {
        float4 w = *(const float4*)&cw[(c + i) * 4];
        float a = x0[i] * w.x + x1[i] * w.y + x2[i] * w.z + x3[i] * w.w;
        v[i] = a / (1.f + expf(-a));
        ss += v[i] * v[i];
    }
    if (part < 2) {   // q/k: l2norm over 128-ch head = 16 consecutive lanes
        ss = row16_allreduce(ss);
        float rn = rsqrtf(ss + 1e-6f);
#pragma unroll
        for (int i = 0; i < 8; ++i) v[i] *= rn;
    }
    uint4 o = make_uint4(pack2(v[0], v[1]), pack2(v[2], v[3]), pack2(v[4], v[5]), pack2(v[6], v[7]));
    *(uint4*)&out[(long)bs * 8192 + c] = o;
}

// ---------- sequential gated delta scan (round-6 shape + packed-f32 math) ----------
// grid 512 = (b, h, col-block of 16); 256 threads = 4 waves; rg=lane&15 owns 8 rows
// (4 f32x2); cloc=(tid>>6)*4+(lane>>4). DPP 16-lane reduces; v_pk_fma_f32 math.
__global__ __launch_bounds__(256) void scan_kernel(const u16* __restrict__ conv,
                                                   const float* __restrict__ gbuf,
                                                   const float* __restrict__ bbuf,
                                                   u16* __restrict__ obuf)
{
    __shared__ __align__(16) u16 lq16[32 * 128];
    __shared__ __align__(16) u16 lk16[32 * 128];
    __shared__ __align__(16) u16 lv16[32 * 16];
    __shared__ float lgb[64];   // interleaved {eg, be}

    const int bid = blockIdx.x;
    const int b = bid >> 8;
    const int h = (bid >> 3) & 31;
    const int c0 = (bid & 7) * 16;
    const int hk = h >> 1;
    const int tid = threadIdx.x;
    const int lane = tid & 63;
    const int rg = lane & 15;
    const int cloc = (tid >> 6) * 4 + (lane >> 4);   // 0..15
    const long rowbase = (long)b * 2048;
    const float scale = 0.08838834764831845f;  // 128^-0.5

    f32x2 S2[4];
#pragma unroll
    for (int i = 0; i < 4; ++i) S2[i] = (f32x2){0.f, 0.f};

    for (int t0 = 0; t0 < 2048; t0 += 32) {
        __syncthreads();
        // stage q,k raw bf16: 512 uint4 each, direct global->LDS
        {
            const int tt = tid >> 4, u4 = tid & 15;
            const long base = (rowbase + t0 + tt) * 8192;
            async16(&conv[base + hk * 128 + u4 * 8], &lq16[tid * 8]);
            async16(&conv[base + 2048 + hk * 128 + u4 * 8], &lk16[tid * 8]);
        }
        {
            const int id = tid + 256;
            const int tt = id >> 4, u4 = id & 15;
            const long base = (rowbase + t0 + tt) * 8192;
            async16(&conv[base + hk * 128 + u4 * 8], &lq16[id * 8]);
            async16(&conv[base + 2048 + hk * 128 + u4 * 8], &lk16[id * 8]);
        }
        if (tid < 64) {
            const int tt = tid >> 1, c8 = (tid & 1) * 8;
            async16(&conv[(rowbase + t0 + tt) * 8192 + 4096 + h * 128 + c0 + c8], &lv16[tid * 8]);
        }
        if (tid < 32) {
            lgb[2 * tid]     = expf(gbuf[(rowbase + t0 + tid) * 32 + h]);
            lgb[2 * tid + 1] = bbuf[(rowbase + t0 + tid) * 32 + h];
        }
        __syncthreads();

        f32x2 k2[2][4], q2[2][4];
        float vvp[2], egp[2], bep[2];
        {
            uint4 kw = *(const uint4*)&lk16[rg * 8];
            uint4 qw = *(const uint4*)&lq16[rg * 8];
            unpack8p(kw, k2[0]); unpack8p(qw, q2[0]);
            vvp[0] = bf2f(lv16[cloc]); egp[0] = lgb[0]; bep[0] = lgb[1];
        }
#pragma unroll
        for (int tt = 0; tt < 32; ++tt) {
            const int cur = tt & 1, nxt = cur ^ 1;
            if (tt < 31) {  // prefetch + unpack t+1 while computing t
                uint4 kw = *(const uint4*)&lk16[(tt + 1) * 128 + rg * 8];
                uint4 qw = *(const uint4*)&lq16[(tt + 1) * 128 + rg * 8];
                unpack8p(kw, k2[nxt]); unpack8p(qw, q2[nxt]);
                vvp[nxt] = bf2f(lv16[(tt + 1) * 16 + cloc]);
                egp[nxt] = lgb[2 * tt + 2]; bep[nxt] = lgb[2 * tt + 3];
            }
            const float eg = egp[cur], be = bep[cur], vv = vvp[cur];
            const f32x2* k4 = k2[cur];
            const f32x2* q4 = q2[cur];
            f32x2 pa = k4[0] * S2[0];
            f32x2 pb = k4[1] * S2[1];
            pa = pk_fma(k4[2], S2[2], pa);
            pb = pk_fma(k4[3], S2[3], pb);
            pa = pa + pb;
            const float pp = row16_allreduce(pa.x + pa.y);
            const float delta = be * (vv - pp * eg);
            const f32x2 eg2 = {eg, eg}, de2 = {delta, delta};
#pragma unroll
            for (int j = 0; j < 4; ++j)
                S2[j] = pk_fma(S2[j], eg2, k4[j] * de2);
            f32x2 oa = q4[0] * S2[0];
            f32x2 ob = q4[1] * S2[1];
            oa = pk_fma(q4[2], S2[2], oa);
            ob = pk_fma(q4[3], S2[3], ob);
            oa = oa + ob;
            const float oo = row16_allreduce(oa.x + oa.y);
            if (rg == 0)
                obuf[((rowbase + t0 + tt) * 32 + h) * 128 + c0 + cloc] = f2bf(oo * scale);
        }
    }
}

// ---------- RMS-norm + gating: y = o*rsqrt(mean(o^2)+eps) * norm_w * silu(z) ----------
__global__ __launch_bounds__(128) void gate_kernel(const u16* __restrict__ obuf,
                                                   const u16* __restrict__ qkvz,
                                                   const float* __restrict__ norm_w,
                                                   u16* __restrict__ ybuf)
{
    const int bid = blockIdx.x;          // bs*32 + hv
    const int bs = bid >> 5, hv = bid & 31;
    const int dv = threadIdx.x;
    __shared__ float red[2];
    float v = bf2f(obuf[(long)bid * 128 + dv]);
    float ss = v * v;
    ss += __shfl_xor(ss, 1);  ss += __shfl_xor(ss, 2);  ss += __shfl_xor(ss, 4);
    ss += __shfl_xor(ss, 8);  ss += __shfl_xor(ss, 16); ss += __shfl_xor(ss, 32);
    if ((dv & 63) == 0) red[dv >> 6] = ss;
    __syncthreads();
    const float mean = (red[0] + red[1]) * (1.f / 128.f);
    const float rstd = rsqrtf(mean + 1e-6f);
    const int hk = hv >> 1;
    const float z = bf2f(qkvz[(long)bs * 12288 + hk * 768 + 512 + (hv & 1) * 128 + dv]);
    const float y = v * rstd * norm_w[dv] * (z / (1.f + expf(-z)));
    ybuf[(long)bs * 4096 + hv * 128 + dv] = f2bf(y);
}

// ---------- launch ----------
extern "C" void kernel_launch(void* const* d_in, const int* in_sizes, int n_in,
                              void* d_out, int out_size, void* d_ws, size_t ws_size,
                              hipStream_t stream)
{
    const float* hs      = (const float*)d_in[0];
    const float* w_qkvz  = (const float*)d_in[1];
    const float* w_ba    = (const float*)d_in[2];
    const float* conv_w  = (const float*)d_in[3];
    const float* A_log   = (const float*)d_in[4];
    const float* dt_bias = (const float*)d_in[5];
    const float* norm_w  = (const float*)d_in[6];
    const float* w_out   = (const float*)d_in[7];

    char* ws = (char*)d_ws;
    u16*   qkvz   = (u16*)ws;                          // 100,663,296 B
    u16*   convb  = (u16*)(ws + 100663296);            //  67,108,864 B
    float* gbuf   = (float*)(ws + 167772160);          //     524,288 B
    float* bbuf   = (float*)(ws + 168296448);          //     524,288 B
    char*  regE   = ws + 168820736;                    //  33,554,432 B (end 202,375,168)
    u16*   hs_b   = (u16*)regE;                        // bf16 hs (dead after GEMM1)
    u16*   obuf   = (u16*)regE;                        // overwrites hs_b at scan time
    u16*   wqkvz_t = convb;                            // bf16 w_qkvz^T (dead after GEMM1; conv overwrites)
    u16*   ybuf   = convb;                             // gate output (conv data dead after scan)
    u16*   wout_t = qkvz;                              // bf16 w_out^T (qkvz dead after gate)

    // 1) dtype prep
    f2b_kernel<<<4096, 256, 0, stream>>>(hs, hs_b);                            // 4096*2048
    transpose_f2b<<<dim3(384, 64), 256, 0, stream>>>(w_qkvz, wqkvz_t, 2048, 12288);
    // 2) qkvz = hs @ w_qkvz  (4096 x 12288 x 2048), bf16 out
    gemm_bt<0><<<dim3(96, 32), 256, 0, stream>>>(hs_b, wqkvz_t, qkvz, 4096, 12288, 2048);
    // 3) g/beta
    ba_kernel<<<1024, 256, 0, stream>>>(hs, w_ba, A_log, dt_bias, gbuf, bbuf);
    // 4) conv + silu + l2norm (overwrites wqkvz_t region)
    conv_kernel<<<4096 * 4, 256, 0, stream>>>(qkvz, conv_w, convb);
    // 5) gated delta scan (overwrites hs_b region)
    scan_kernel<<<512, 256, 0, stream>>>(convb, gbuf, bbuf, obuf);
    // 6) gating (writes ybuf = convb region)
    gate_kernel<<<4096 * 32, 128, 0, stream>>>(obuf, qkvz, norm_w, ybuf);
    // 7) w_out^T into qkvz region (dead), then out = y @ w_out (4096 x 2048 x 4096), fp32 out
    transpose_f2b<<<dim3(64, 128), 256, 0, stream>>>(w_out, wout_t, 4096, 2048);
    gemm_bt<1><<<dim3(16, 32), 256, 0, stream>>>(ybuf, wout_t, d_out, 4096, 2048, 4096);
}